// Round 1
// baseline (3617.151 us; speedup 1.0000x reference)
//
#include <hip/hip_runtime.h>

#define CI_BLK 8

// ---------------------------------------------------------------------------
// 3x3 conv, pad 1, stride 1.  Block: 32(W) x 8(H) outputs x 16 c_out.
// Thread: 4 consecutive cols x 1 row x 4 c_out = 16 accumulators.
// Requires W%32==0, H%8==0, C_out%16==0, C_in%CI_BLK==0.
// ---------------------------------------------------------------------------
__global__ __launch_bounds__(256) void conv3x3_s1(
    const float* __restrict__ in, const float* __restrict__ wgt,
    const float* __restrict__ bias, float* __restrict__ out,
    int C_in, int C_out, int H, int W, int relu)
{
    __shared__ float s_in[CI_BLK][10][34];
    __shared__ float s_w[16][CI_BLK][9];

    const int tid  = threadIdx.x;
    const int g    = tid >> 6;      // c_out group 0..3
    const int lane = tid & 63;
    const int ty   = lane >> 3;     // 0..7
    const int tx   = lane & 7;      // 0..7

    const int nCoBlk = C_out >> 4;
    const int b    = blockIdx.z / nCoBlk;
    const int coB  = (blockIdx.z - b * nCoBlk) << 4;
    const int row0 = blockIdx.y << 3;
    const int col0 = blockIdx.x << 5;

    float acc[4][4];
    #pragma unroll
    for (int k = 0; k < 4; ++k)
      #pragma unroll
      for (int p = 0; p < 4; ++p) acc[k][p] = 0.f;

    const int HW = H * W;
    const int in_base = b * C_in * HW;

    for (int ci0 = 0; ci0 < C_in; ci0 += CI_BLK) {
      __syncthreads();
      // stage input tile (with halo, zero-padded at image edges)
      for (int idx = tid; idx < CI_BLK * 340; idx += 256) {
        int ci  = idx / 340;
        int rem = idx - ci * 340;
        int ri  = rem / 34;
        int cc  = rem - ri * 34;
        int gr  = row0 - 1 + ri;
        int gc  = col0 - 1 + cc;
        float v = 0.f;
        if ((unsigned)gr < (unsigned)H && (unsigned)gc < (unsigned)W)
          v = in[in_base + (ci0 + ci) * HW + gr * W + gc];
        s_in[ci][ri][cc] = v;
      }
      // stage weights for this (c_out block, c_in chunk)
      for (int idx = tid; idx < 16 * CI_BLK * 9; idx += 256) {
        int co  = idx / (CI_BLK * 9);
        int rem = idx - co * (CI_BLK * 9);
        int ci  = rem / 9;
        int k   = rem - ci * 9;
        s_w[co][ci][k] = wgt[((coB + co) * C_in + ci0 + ci) * 9 + k];
      }
      __syncthreads();
      #pragma unroll
      for (int ci = 0; ci < CI_BLK; ++ci) {
        float xv[3][6];
        #pragma unroll
        for (int dr = 0; dr < 3; ++dr)
          #pragma unroll
          for (int dc = 0; dc < 6; ++dc)
            xv[dr][dc] = s_in[ci][ty + dr][(tx << 2) + dc];
        #pragma unroll
        for (int k = 0; k < 4; ++k) {
          const float* wp = &s_w[(g << 2) + k][ci][0];
          const float w0 = wp[0], w1 = wp[1], w2 = wp[2],
                      w3 = wp[3], w4 = wp[4], w5 = wp[5],
                      w6 = wp[6], w7 = wp[7], w8 = wp[8];
          #pragma unroll
          for (int p = 0; p < 4; ++p) {
            acc[k][p] += w0 * xv[0][p] + w1 * xv[0][p + 1] + w2 * xv[0][p + 2]
                       + w3 * xv[1][p] + w4 * xv[1][p + 1] + w5 * xv[1][p + 2]
                       + w6 * xv[2][p] + w7 * xv[2][p + 1] + w8 * xv[2][p + 2];
          }
        }
      }
    }

    const int out_row = row0 + ty;
    const int out_col = col0 + (tx << 2);
    const int ob = b * C_out * HW;
    #pragma unroll
    for (int k = 0; k < 4; ++k) {
      const float bv = bias ? bias[coB + (g << 2) + k] : 0.f;
      float4 v;
      v.x = acc[k][0] + bv; v.y = acc[k][1] + bv;
      v.z = acc[k][2] + bv; v.w = acc[k][3] + bv;
      if (relu) {
        v.x = fmaxf(v.x, 0.f); v.y = fmaxf(v.y, 0.f);
        v.z = fmaxf(v.z, 0.f); v.w = fmaxf(v.w, 0.f);
      }
      *(float4*)&out[ob + (coB + (g << 2) + k) * HW + out_row * W + out_col] = v;
    }
}

// ---------------------------------------------------------------------------
// 3x3 conv, pad 1, stride 2.  Block: 16(W) x 8(H) outputs x 16 c_out.
// Thread: 2 cols x 1 row x 4 c_out = 8 accumulators.
// Requires W_out%16==0, H_out%8==0, C_out%16==0, C_in%CI_BLK==0.
// ---------------------------------------------------------------------------
__global__ __launch_bounds__(256) void conv3x3_s2(
    const float* __restrict__ in, const float* __restrict__ wgt,
    const float* __restrict__ bias, float* __restrict__ out,
    int C_in, int C_out, int H_in, int W_in, int relu)
{
    __shared__ float s_in[CI_BLK][17][33];
    __shared__ float s_w[16][CI_BLK][9];

    const int tid  = threadIdx.x;
    const int g    = tid >> 6;
    const int lane = tid & 63;
    const int ty   = lane >> 3;
    const int tx   = lane & 7;

    const int H_out = H_in >> 1, W_out = W_in >> 1;
    const int nCoBlk = C_out >> 4;
    const int b    = blockIdx.z / nCoBlk;
    const int coB  = (blockIdx.z - b * nCoBlk) << 4;
    const int row0 = blockIdx.y << 3;   // output rows
    const int col0 = blockIdx.x << 4;   // output cols

    float acc[4][2];
    #pragma unroll
    for (int k = 0; k < 4; ++k) { acc[k][0] = 0.f; acc[k][1] = 0.f; }

    const int HWi = H_in * W_in;
    const int in_base = b * C_in * HWi;

    for (int ci0 = 0; ci0 < C_in; ci0 += CI_BLK) {
      __syncthreads();
      for (int idx = tid; idx < CI_BLK * 561; idx += 256) {
        int ci  = idx / 561;
        int rem = idx - ci * 561;
        int ri  = rem / 33;
        int cc  = rem - ri * 33;
        int gr  = (row0 << 1) - 1 + ri;
        int gc  = (col0 << 1) - 1 + cc;
        float v = 0.f;
        if ((unsigned)gr < (unsigned)H_in && (unsigned)gc < (unsigned)W_in)
          v = in[in_base + (ci0 + ci) * HWi + gr * W_in + gc];
        s_in[ci][ri][cc] = v;
      }
      for (int idx = tid; idx < 16 * CI_BLK * 9; idx += 256) {
        int co  = idx / (CI_BLK * 9);
        int rem = idx - co * (CI_BLK * 9);
        int ci  = rem / 9;
        int k   = rem - ci * 9;
        s_w[co][ci][k] = wgt[((coB + co) * C_in + ci0 + ci) * 9 + k];
      }
      __syncthreads();
      #pragma unroll
      for (int ci = 0; ci < CI_BLK; ++ci) {
        float xv[3][5];
        #pragma unroll
        for (int dr = 0; dr < 3; ++dr)
          #pragma unroll
          for (int dc = 0; dc < 5; ++dc)
            xv[dr][dc] = s_in[ci][(ty << 1) + dr][(tx << 2) + dc];
        #pragma unroll
        for (int k = 0; k < 4; ++k) {
          const float* wp = &s_w[(g << 2) + k][ci][0];
          const float w0 = wp[0], w1 = wp[1], w2 = wp[2],
                      w3 = wp[3], w4 = wp[4], w5 = wp[5],
                      w6 = wp[6], w7 = wp[7], w8 = wp[8];
          #pragma unroll
          for (int p = 0; p < 2; ++p) {
            const int o = p << 1;
            acc[k][p] += w0 * xv[0][o] + w1 * xv[0][o + 1] + w2 * xv[0][o + 2]
                       + w3 * xv[1][o] + w4 * xv[1][o + 1] + w5 * xv[1][o + 2]
                       + w6 * xv[2][o] + w7 * xv[2][o + 1] + w8 * xv[2][o + 2];
          }
        }
      }
    }

    const int out_row = row0 + ty;
    const int out_col = col0 + (tx << 1);
    const int HWo = H_out * W_out;
    const int ob = b * C_out * HWo;
    #pragma unroll
    for (int k = 0; k < 4; ++k) {
      const float bv = bias ? bias[coB + (g << 2) + k] : 0.f;
      float2 v;
      v.x = acc[k][0] + bv; v.y = acc[k][1] + bv;
      if (relu) { v.x = fmaxf(v.x, 0.f); v.y = fmaxf(v.y, 0.f); }
      *(float2*)&out[ob + (coB + (g << 2) + k) * HWo + out_row * W_out + out_col] = v;
    }
}

// ---------------------------------------------------------------------------
// Deformable bilinear sampling with the "faithful raw reshape" semantics:
// for output linear index i = (b*C+c)*HW + q, the (r,c) offsets are
// ((const float2*)off)[i]  (channel pair (2c,2c+1) read as interleaved pairs).
// HW and W are powers of two -> pure bit ops.
// ---------------------------------------------------------------------------
__global__ __launch_bounds__(256) void deform_sample(
    const float* __restrict__ x, const float* __restrict__ off,
    float* __restrict__ out, int lhw, int lw, int H, int W, int total)
{
    int i = blockIdx.x * 256 + threadIdx.x;
    if (i >= total) return;
    const int HWm  = (1 << lhw) - 1;
    const int q    = i & HWm;
    const int base = i & ~HWm;          // (b*C+c)*HW
    const int row  = q >> lw;
    const int col  = q & ((1 << lw) - 1);

    const float2 o2 = ((const float2*)off)[i];
    const float r = fminf(fmaxf(o2.x + (float)row, 0.f), (float)(H - 1));
    const float c = fminf(fmaxf(o2.y + (float)col, 0.f), (float)(W - 1));
    const float rf = floorf(r), cf = floorf(c);
    const int r0 = (int)rf,        c0 = (int)cf;
    const int r1 = (int)ceilf(r),  c1 = (int)ceilf(c);

    const float* xb = x + base;
    const float v_lt = xb[r0 * W + c0];
    const float v_rb = xb[r1 * W + c1];
    const float v_lb = xb[r0 * W + c1];
    const float v_rt = xb[r1 * W + c0];
    const float fr = r - rf, fc = c - cf;
    const float vt = v_lt + (v_rt - v_lt) * fr;
    const float vb = v_lb + (v_rb - v_lb) * fr;
    out[i] = vt + (vb - vt) * fc;
}

// ---------------------------------------------------------------------------
// Global average pool: one block per (b,c), HW elements each.
// ---------------------------------------------------------------------------
__global__ __launch_bounds__(256) void avgpool(
    const float* __restrict__ in, float* __restrict__ out, int HW, float inv)
{
    const int bc = blockIdx.x;
    const float* p = in + bc * HW;
    float s = 0.f;
    for (int i = threadIdx.x; i < HW; i += 256) s += p[i];
    #pragma unroll
    for (int o = 32; o > 0; o >>= 1) s += __shfl_down(s, o, 64);
    __shared__ float red[4];
    if ((threadIdx.x & 63) == 0) red[threadIdx.x >> 6] = s;
    __syncthreads();
    if (threadIdx.x == 0) out[bc] = (red[0] + red[1] + red[2] + red[3]) * inv;
}

__global__ __launch_bounds__(256) void sentinel(float* out, int n, float v)
{
    int i = blockIdx.x * 256 + threadIdx.x;
    if (i < n) out[i] = v;
}

extern "C" void kernel_launch(void* const* d_in, const int* in_sizes, int n_in,
                              void* d_out, int out_size, void* d_ws, size_t ws_size,
                              hipStream_t stream) {
    (void)in_sizes; (void)n_in; (void)out_size;
    const float* x   = (const float*)d_in[0];
    const float* w1  = (const float*)d_in[1];
    const float* b1  = (const float*)d_in[2];
    const float* ow1 = (const float*)d_in[3];
    const float* w2  = (const float*)d_in[4];
    const float* b2  = (const float*)d_in[5];
    const float* ow2 = (const float*)d_in[6];
    const float* w3  = (const float*)d_in[7];
    const float* b3  = (const float*)d_in[8];
    const float* ow3 = (const float*)d_in[9];
    const float* w4  = (const float*)d_in[10];
    const float* b4  = (const float*)d_in[11];
    float* out = (float*)d_out;
    float* ws  = (float*)d_ws;

    // Workspace regions (floats). A: activations, Br: offsets, Cr: deform out.
    const size_t A_sz = 33554432;   // 16*32*256*256  (max of h1,h2,h3,h4)
    const size_t B_sz = 67108864;   // 16*64*256*256  (max of off1,off2,off3)
    const size_t C_sz = 33554432;   // deform outputs
    const size_t needed = (A_sz + B_sz + C_sz) * sizeof(float);
    if (ws_size < needed) {
        // diagnosable failure: absmax ~12345 means workspace too small
        sentinel<<<2, 256, 0, stream>>>(out, 512, 12345.0f);
        return;
    }
    float* hA = ws;
    float* oB = ws + A_sz;
    float* dC = ws + A_sz + B_sz;

    // L1: conv1 (32->32, 256x256, s1, relu)
    conv3x3_s1<<<dim3(8, 32, 32), 256, 0, stream>>>(x, w1, b1, hA, 32, 32, 256, 256, 1);
    // offconv1 (32->64, 256x256, s1)
    conv3x3_s1<<<dim3(8, 32, 64), 256, 0, stream>>>(hA, ow1, nullptr, oB, 32, 64, 256, 256, 0);
    // deform sample 1: 16*32*65536 elements
    deform_sample<<<131072, 256, 0, stream>>>(hA, oB, dC, 16, 8, 256, 256, 33554432);

    // L2: conv2 (32->64, s2, relu): in 256x256 -> out 128x128
    conv3x3_s2<<<dim3(8, 16, 64), 256, 0, stream>>>(dC, w2, b2, hA, 32, 64, 256, 256, 1);
    // offconv2 (64->128, 128x128, s1)
    conv3x3_s1<<<dim3(4, 16, 128), 256, 0, stream>>>(hA, ow2, nullptr, oB, 64, 128, 128, 128, 0);
    // deform sample 2: 16*64*16384 elements
    deform_sample<<<65536, 256, 0, stream>>>(hA, oB, dC, 14, 7, 128, 128, 16777216);

    // L3: conv3 (64->32, s2, relu): in 128x128 -> out 64x64
    conv3x3_s2<<<dim3(4, 8, 32), 256, 0, stream>>>(dC, w3, b3, hA, 64, 32, 128, 128, 1);
    // offconv3 (32->64, 64x64, s1)
    conv3x3_s1<<<dim3(2, 8, 64), 256, 0, stream>>>(hA, ow3, nullptr, oB, 32, 64, 64, 64, 0);
    // deform sample 3: 16*32*4096 elements
    deform_sample<<<8192, 256, 0, stream>>>(hA, oB, dC, 12, 6, 64, 64, 2097152);

    // L4: conv4 (32->32, s2, relu): in 64x64 -> out 32x32
    conv3x3_s2<<<dim3(2, 4, 32), 256, 0, stream>>>(dC, w4, b4, hA, 32, 32, 64, 64, 1);
    // Global average pool over 32*32=1024 -> (16,32)
    avgpool<<<512, 256, 0, stream>>>(hA, out, 1024, 1.0f / 1024.0f);
}

// Round 2
// 743.320 us; speedup vs baseline: 4.8662x; 4.8662x over previous
//
#include <hip/hip_runtime.h>

typedef short short8 __attribute__((ext_vector_type(8)));
typedef float f32x4 __attribute__((ext_vector_type(4)));

__device__ __forceinline__ unsigned short f2b(float f) {
    unsigned u = __float_as_uint(f);
    u += 0x7fffu + ((u >> 16) & 1u);          // round-to-nearest-even
    return (unsigned short)(u >> 16);
}
__device__ __forceinline__ float b2f(unsigned short h) {
    return __uint_as_float(((unsigned)h) << 16);
}

// ---------------------------------------------------------------------------
// 3x3 conv, pad 1, stride 1, NHWC bf16 in/out, bf16 MFMA, fp32 accum.
// Block: 16x16 output pixels x 32 c_out. 4 waves; wave = 4 rows x 32 c_out.
// Weights pre-transformed to [tap][C_OUT][C_IN] bf16.
// ---------------------------------------------------------------------------
template <int C_IN, int C_OUT>
__global__ __launch_bounds__(256) void conv_s1_mfma(
    const unsigned short* __restrict__ in, const unsigned short* __restrict__ wT,
    const float* __restrict__ bias, unsigned short* __restrict__ out,
    int H, int W, int relu)
{
    constexpr int LDSTR  = C_IN + 8;     // pixel stride (elems): 80/144 B -> 16B aligned, 2-way banks
    constexpr int KSTEPS = C_IN / 32;
    constexpr int CH8    = C_IN / 8;
    __shared__ unsigned short s_in[18 * 18 * LDSTR];

    const int tid   = threadIdx.x;
    const int wv    = tid >> 6;
    const int lane  = tid & 63;
    const int mlane = lane & 15;
    const int quad  = lane >> 4;

    const int nCo  = C_OUT / 32;
    const int b    = blockIdx.z / nCo;
    const int coB  = (blockIdx.z - b * nCo) * 32;
    const int row0 = blockIdx.y * 16;
    const int col0 = blockIdx.x * 16;

    // stage 18x18 halo tile, all C_IN channels, 16B chunks
    for (int idx = tid; idx < 18 * 18 * CH8; idx += 256) {
        int pixel = idx / CH8;
        int ch    = (idx - pixel * CH8) * 8;
        int pr    = pixel / 18;
        int pc    = pixel - pr * 18;
        int gr = row0 - 1 + pr, gc = col0 - 1 + pc;
        ulonglong2 v; v.x = 0; v.y = 0;
        if ((unsigned)gr < (unsigned)H && (unsigned)gc < (unsigned)W)
            v = *(const ulonglong2*)&in[((b * H + gr) * W + gc) * C_IN + ch];
        *(ulonglong2*)&s_in[pixel * LDSTR + ch] = v;
    }
    __syncthreads();

    f32x4 acc[2][4];
    #pragma unroll
    for (int mt = 0; mt < 2; ++mt)
        #pragma unroll
        for (int t = 0; t < 4; ++t) acc[mt][t] = (f32x4)(0.f);

    #pragma unroll 1
    for (int kk = 0; kk < KSTEPS; ++kk) {
        short8 A[2][9];
        #pragma unroll
        for (int mt = 0; mt < 2; ++mt)
            #pragma unroll
            for (int tap = 0; tap < 9; ++tap)
                A[mt][tap] = *(const short8*)&wT[(tap * C_OUT + coB + mt * 16 + mlane) * C_IN
                                                 + kk * 32 + quad * 8];

        const unsigned short* sb =
            &s_in[(wv * 4 * 18 + mlane) * LDSTR + kk * 32 + quad * 8];
        #pragma unroll
        for (int t = 0; t < 4; ++t) {
            #pragma unroll
            for (int tap = 0; tap < 9; ++tap) {
                const int dy = tap / 3, dx = tap % 3;
                short8 Bf = *(const short8*)&sb[((t + dy) * 18 + dx) * LDSTR];
                acc[0][t] = __builtin_amdgcn_mfma_f32_16x16x32_bf16(A[0][tap], Bf, acc[0][t], 0, 0, 0);
                acc[1][t] = __builtin_amdgcn_mfma_f32_16x16x32_bf16(A[1][tap], Bf, acc[1][t], 0, 0, 0);
            }
        }
    }

    // epilogue: C/D layout col=lane&15 (pixel), row=quad*4+reg (c_out)
    #pragma unroll
    for (int mt = 0; mt < 2; ++mt) {
        const int cb = coB + mt * 16 + quad * 4;
        float4 bv;
        if (bias) bv = *(const float4*)&bias[cb]; else { bv.x = bv.y = bv.z = bv.w = 0.f; }
        #pragma unroll
        for (int t = 0; t < 4; ++t) {
            const int row = row0 + wv * 4 + t, col = col0 + mlane;
            float o0 = acc[mt][t][0] + bv.x, o1 = acc[mt][t][1] + bv.y;
            float o2 = acc[mt][t][2] + bv.z, o3 = acc[mt][t][3] + bv.w;
            if (relu) {
                o0 = fmaxf(o0, 0.f); o1 = fmaxf(o1, 0.f);
                o2 = fmaxf(o2, 0.f); o3 = fmaxf(o3, 0.f);
            }
            ushort4 pk; pk.x = f2b(o0); pk.y = f2b(o1); pk.z = f2b(o2); pk.w = f2b(o3);
            *(ushort4*)&out[((b * H + row) * W + col) * C_OUT + cb] = pk;
        }
    }
}

// ---------------------------------------------------------------------------
// 3x3 conv, pad 1, stride 2, NHWC bf16. Block: 8x8 out pixels x 32 c_out.
// Wave = 1 n-tile (16 px spanning 2 rows x 8 cols) x 32 c_out.
// ---------------------------------------------------------------------------
template <int C_IN, int C_OUT>
__global__ __launch_bounds__(256) void conv_s2_mfma(
    const unsigned short* __restrict__ in, const unsigned short* __restrict__ wT,
    const float* __restrict__ bias, unsigned short* __restrict__ out,
    int H_in, int W_in, int relu)
{
    constexpr int LDSTR  = C_IN + 8;
    constexpr int KSTEPS = C_IN / 32;
    constexpr int CH8    = C_IN / 8;
    __shared__ unsigned short s_in[17 * 17 * LDSTR];

    const int tid   = threadIdx.x;
    const int wv    = tid >> 6;
    const int lane  = tid & 63;
    const int mlane = lane & 15;
    const int quad  = lane >> 4;

    const int H_out = H_in >> 1, W_out = W_in >> 1;
    const int nCo   = C_OUT / 32;
    const int b     = blockIdx.z / nCo;
    const int coB   = (blockIdx.z - b * nCo) * 32;
    const int orow0 = blockIdx.y * 8, ocol0 = blockIdx.x * 8;
    const int irow0 = orow0 * 2 - 1,  icol0 = ocol0 * 2 - 1;

    for (int idx = tid; idx < 17 * 17 * CH8; idx += 256) {
        int pixel = idx / CH8;
        int ch    = (idx - pixel * CH8) * 8;
        int pr    = pixel / 17;
        int pc    = pixel - pr * 17;
        int gr = irow0 + pr, gc = icol0 + pc;
        ulonglong2 v; v.x = 0; v.y = 0;
        if ((unsigned)gr < (unsigned)H_in && (unsigned)gc < (unsigned)W_in)
            v = *(const ulonglong2*)&in[((b * H_in + gr) * W_in + gc) * C_IN + ch];
        *(ulonglong2*)&s_in[pixel * LDSTR + ch] = v;
    }
    __syncthreads();

    f32x4 acc[2];
    acc[0] = (f32x4)(0.f); acc[1] = (f32x4)(0.f);

    const int plr = wv * 2 + (mlane >> 3);   // local out row 0..7
    const int plc = mlane & 7;               // local out col 0..7

    #pragma unroll 1
    for (int kk = 0; kk < KSTEPS; ++kk) {
        short8 A[2][9];
        #pragma unroll
        for (int mt = 0; mt < 2; ++mt)
            #pragma unroll
            for (int tap = 0; tap < 9; ++tap)
                A[mt][tap] = *(const short8*)&wT[(tap * C_OUT + coB + mt * 16 + mlane) * C_IN
                                                 + kk * 32 + quad * 8];

        const unsigned short* sb =
            &s_in[(plr * 2 * 17 + plc * 2) * LDSTR + kk * 32 + quad * 8];
        #pragma unroll
        for (int tap = 0; tap < 9; ++tap) {
            const int dy = tap / 3, dx = tap % 3;
            short8 Bf = *(const short8*)&sb[(dy * 17 + dx) * LDSTR];
            acc[0] = __builtin_amdgcn_mfma_f32_16x16x32_bf16(A[0][tap], Bf, acc[0], 0, 0, 0);
            acc[1] = __builtin_amdgcn_mfma_f32_16x16x32_bf16(A[1][tap], Bf, acc[1], 0, 0, 0);
        }
    }

    const int row = orow0 + plr, col = ocol0 + plc;
    #pragma unroll
    for (int mt = 0; mt < 2; ++mt) {
        const int cb = coB + mt * 16 + quad * 4;
        float4 bv;
        if (bias) bv = *(const float4*)&bias[cb]; else { bv.x = bv.y = bv.z = bv.w = 0.f; }
        float o0 = acc[mt][0] + bv.x, o1 = acc[mt][1] + bv.y;
        float o2 = acc[mt][2] + bv.z, o3 = acc[mt][3] + bv.w;
        if (relu) {
            o0 = fmaxf(o0, 0.f); o1 = fmaxf(o1, 0.f);
            o2 = fmaxf(o2, 0.f); o3 = fmaxf(o3, 0.f);
        }
        ushort4 pk; pk.x = f2b(o0); pk.y = f2b(o1); pk.z = f2b(o2); pk.w = f2b(o3);
        *(ushort4*)&out[((b * H_out + row) * W_out + col) * C_OUT + cb] = pk;
    }
}

// ---------------------------------------------------------------------------
// Deformable bilinear sampling, NHWC bf16. Faithful-reshape offset semantics:
// for (b, c_img, q): j-th coord at NCHW-flat b*2C*HW + c_img*2HW + 2q + j,
// i.e. channel k = 2c + (2q+j)>>lhw, pos m = (2q+j)&(HW-1), read from NHWC.
// ---------------------------------------------------------------------------
__global__ __launch_bounds__(256) void deform_nhwc(
    const unsigned short* __restrict__ x, const unsigned short* __restrict__ off,
    unsigned short* __restrict__ out, int lc, int lhw, int lw, int total)
{
    const int i = blockIdx.x * 256 + threadIdx.x;
    if (i >= total) return;
    const int C = 1 << lc, HW = 1 << lhw, W = 1 << lw;
    const int H = HW >> lw;
    const int ci  = i & (C - 1);
    const int pix = i >> lc;              // b*HW + q
    const int q   = pix & (HW - 1);
    const int b   = pix >> lhw;
    const int r   = q >> lw, c = q & (W - 1);

    const int t0 = q << 1, t1 = t0 + 1;
    const int k0 = (ci << 1) + (t0 >> lhw), m0 = t0 & (HW - 1);
    const int k1 = (ci << 1) + (t1 >> lhw), m1 = t1 & (HW - 1);
    const int ob = b << lhw;
    const int C2 = C << 1;

    const float roff = b2f(off[(ob + m0) * C2 + k0]);
    const float coff = b2f(off[(ob + m1) * C2 + k1]);
    const float rr = fminf(fmaxf(roff + (float)r, 0.f), (float)(H - 1));
    const float cc = fminf(fmaxf(coff + (float)c, 0.f), (float)(W - 1));
    const float rf = floorf(rr), cf = floorf(cc);
    const int r0 = (int)rf, c0 = (int)cf;
    const int r1 = (int)ceilf(rr), c1 = (int)ceilf(cc);

    const float v_lt = b2f(x[((ob + (r0 << lw) + c0) << lc) + ci]);
    const float v_rb = b2f(x[((ob + (r1 << lw) + c1) << lc) + ci]);
    const float v_lb = b2f(x[((ob + (r0 << lw) + c1) << lc) + ci]);
    const float v_rt = b2f(x[((ob + (r1 << lw) + c0) << lc) + ci]);
    const float fr = rr - rf, fc = cc - cf;
    const float vt = v_lt + (v_rt - v_lt) * fr;
    const float vb = v_lb + (v_rb - v_lb) * fr;
    out[i] = f2b(vt + (vb - vt) * fc);
}

// ---------------------------------------------------------------------------
// x: fp32 NCHW (C=32) -> bf16 NHWC via LDS transpose. Block: 32ch x 64 px.
// ---------------------------------------------------------------------------
__global__ __launch_bounds__(256) void nchw2nhwc(
    const float* __restrict__ x, unsigned short* __restrict__ out, int HW)
{
    __shared__ float s[32][65];
    const int b = blockIdx.y, p0 = blockIdx.x * 64;
    const int tid = threadIdx.x;
    #pragma unroll
    for (int k = 0; k < 8; ++k) {
        int e = tid + k * 256, ci = e >> 6, p = e & 63;
        s[ci][p] = x[(b * 32 + ci) * HW + p0 + p];
    }
    __syncthreads();
    #pragma unroll
    for (int k = 0; k < 8; ++k) {
        int e = tid + k * 256, p = e >> 5, ci = e & 31;
        out[(b * HW + p0 + p) * 32 + ci] = f2b(s[ci][p]);
    }
}

// weights: fp32 OIHW -> bf16 [tap][C_out][C_in]
__global__ __launch_bounds__(256) void wtrans(
    const float* __restrict__ w, unsigned short* __restrict__ wT,
    int C_out, int C_in, int n)
{
    const int i = blockIdx.x * 256 + threadIdx.x;
    if (i >= n) return;
    const int ci = i % C_in;
    const int rr = i / C_in;
    const int co = rr % C_out;
    const int tap = rr / C_out;
    wT[i] = f2b(w[(co * C_in + ci) * 9 + tap]);
}

// global avg pool over 32x32, NHWC bf16 (C=32) -> fp32 (B,C)
__global__ __launch_bounds__(256) void avgpool_nhwc(
    const unsigned short* __restrict__ in, float* __restrict__ out)
{
    const int b = blockIdx.x, tid = threadIdx.x;
    const int ci = tid & 31, pg = tid >> 5;
    float s = 0.f;
    for (int k = 0; k < 128; ++k) {
        int p = pg * 128 + k;
        s += b2f(in[(b * 1024 + p) * 32 + ci]);
    }
    __shared__ float red[8][32];
    red[pg][ci] = s;
    __syncthreads();
    if (tid < 32) {
        float t = 0.f;
        #pragma unroll
        for (int j = 0; j < 8; ++j) t += red[j][tid];
        out[b * 32 + tid] = t * (1.f / 1024.f);
    }
}

__global__ __launch_bounds__(256) void sentinel(float* out, int n, float v)
{
    int i = blockIdx.x * 256 + threadIdx.x;
    if (i < n) out[i] = v;
}

extern "C" void kernel_launch(void* const* d_in, const int* in_sizes, int n_in,
                              void* d_out, int out_size, void* d_ws, size_t ws_size,
                              hipStream_t stream) {
    (void)in_sizes; (void)n_in; (void)out_size;
    const float* x   = (const float*)d_in[0];
    const float* w1  = (const float*)d_in[1];
    const float* b1  = (const float*)d_in[2];
    const float* ow1 = (const float*)d_in[3];
    const float* w2  = (const float*)d_in[4];
    const float* b2  = (const float*)d_in[5];
    const float* ow2 = (const float*)d_in[6];
    const float* w3  = (const float*)d_in[7];
    const float* b3  = (const float*)d_in[8];
    const float* ow3 = (const float*)d_in[9];
    const float* w4  = (const float*)d_in[10];
    const float* b4  = (const float*)d_in[11];
    float* out = (float*)d_out;
    unsigned short* wsu = (unsigned short*)d_ws;

    // workspace layout (ushort units)
    const size_t XB = 0;                         // 16*256*256*32 = 33554432
    const size_t HA = 33554432;                  // activations (max 33.5M)
    const size_t OB = 67108864;                  // offconv out (max 67.1M)
    const size_t DC = 134217728;                 // deform out  (max 33.5M)
    const size_t WB = 167772160;                 // weights: 165888 total
    const size_t total_us = WB + 165888;
    if (ws_size < total_us * 2) {
        sentinel<<<2, 256, 0, stream>>>(out, 512, 12345.0f);
        return;
    }
    unsigned short* xb = wsu + XB;
    unsigned short* hA = wsu + HA;
    unsigned short* oB = wsu + OB;
    unsigned short* dC = wsu + DC;
    unsigned short* wt1  = wsu + WB;             //  9216
    unsigned short* owt1 = wt1 + 9216;           // 18432
    unsigned short* wt2  = owt1 + 18432;         // 18432
    unsigned short* owt2 = wt2 + 18432;          // 73728
    unsigned short* wt3  = owt2 + 73728;         // 18432
    unsigned short* owt3 = wt3 + 18432;          // 18432
    unsigned short* wt4  = owt3 + 18432;         //  9216

    // weight transforms (tiny)
    wtrans<<<36,  256, 0, stream>>>(w1,  wt1,  32,  32,  9216);
    wtrans<<<72,  256, 0, stream>>>(ow1, owt1, 64,  32, 18432);
    wtrans<<<72,  256, 0, stream>>>(w2,  wt2,  64,  32, 18432);
    wtrans<<<288, 256, 0, stream>>>(ow2, owt2, 128, 64, 73728);
    wtrans<<<72,  256, 0, stream>>>(w3,  wt3,  32,  64, 18432);
    wtrans<<<72,  256, 0, stream>>>(ow3, owt3, 64,  32, 18432);
    wtrans<<<36,  256, 0, stream>>>(w4,  wt4,  32,  32,  9216);

    // input to NHWC bf16
    nchw2nhwc<<<dim3(1024, 16), 256, 0, stream>>>(x, xb, 65536);

    // L1: conv1 (32->32, 256x256, s1, relu)
    conv_s1_mfma<32, 32><<<dim3(16, 16, 16), 256, 0, stream>>>(xb, wt1, b1, hA, 256, 256, 1);
    // offconv1 (32->64)
    conv_s1_mfma<32, 64><<<dim3(16, 16, 32), 256, 0, stream>>>(hA, owt1, nullptr, oB, 256, 256, 0);
    deform_nhwc<<<131072, 256, 0, stream>>>(hA, oB, dC, 5, 16, 8, 33554432);

    // L2: conv2 (32->64, s2) 256->128
    conv_s2_mfma<32, 64><<<dim3(16, 16, 32), 256, 0, stream>>>(dC, wt2, b2, hA, 256, 256, 1);
    // offconv2 (64->128)
    conv_s1_mfma<64, 128><<<dim3(8, 8, 64), 256, 0, stream>>>(hA, owt2, nullptr, oB, 128, 128, 0);
    deform_nhwc<<<65536, 256, 0, stream>>>(hA, oB, dC, 6, 14, 7, 16777216);

    // L3: conv3 (64->32, s2) 128->64
    conv_s2_mfma<64, 32><<<dim3(8, 8, 16), 256, 0, stream>>>(dC, wt3, b3, hA, 128, 128, 1);
    // offconv3 (32->64)
    conv_s1_mfma<32, 64><<<dim3(4, 4, 32), 256, 0, stream>>>(hA, owt3, nullptr, oB, 64, 64, 0);
    deform_nhwc<<<8192, 256, 0, stream>>>(hA, oB, dC, 5, 12, 6, 2097152);

    // L4: conv4 (32->32, s2) 64->32
    conv_s2_mfma<32, 32><<<dim3(4, 4, 16), 256, 0, stream>>>(dC, wt4, b4, hA, 64, 64, 1);
    // pool -> (16,32)
    avgpool_nhwc<<<16, 256, 0, stream>>>(hA, out);
}

// Round 3
// 699.865 us; speedup vs baseline: 5.1684x; 1.0621x over previous
//
#include <hip/hip_runtime.h>

typedef short short8 __attribute__((ext_vector_type(8)));
typedef float f32x4 __attribute__((ext_vector_type(4)));

__device__ __forceinline__ unsigned short f2b(float f) {
    unsigned u = __float_as_uint(f);
    u += 0x7fffu + ((u >> 16) & 1u);          // round-to-nearest-even
    return (unsigned short)(u >> 16);
}
__device__ __forceinline__ float b2f(unsigned short h) {
    return __uint_as_float(((unsigned)h) << 16);
}

// ---------------------------------------------------------------------------
// 3x3 conv, pad 1, stride 1, NHWC bf16, bf16 MFMA fp32 accum.
// Block: 16x16 output pixels x (NW/4) co-blocks of 32 c_out. NW waves.
// Wave = 4 pixel rows x 32 c_out. Weights pre-transformed [tap][C_OUT][C_IN].
// ---------------------------------------------------------------------------
template <int C_IN, int C_OUT, int NW>
__global__ __launch_bounds__(NW * 64) void conv_s1_mfma(
    const unsigned short* __restrict__ in, const unsigned short* __restrict__ wT,
    const float* __restrict__ bias, unsigned short* __restrict__ out,
    int H, int W, int relu)
{
    constexpr int LDSTR  = C_IN + 8;   // 16B-aligned pixel stride, 2-way banks max
    constexpr int KSTEPS = C_IN / 32;
    constexpr int CH8    = C_IN / 8;
    constexpr int COPB   = 32 * (NW / 4);   // c_out per block
    __shared__ unsigned short s_in[18 * 18 * LDSTR];

    const int tid   = threadIdx.x;
    const int wave  = tid >> 6;
    const int wv    = wave & 3;        // row group
    const int csub  = wave >> 2;       // co sub-block
    const int lane  = tid & 63;
    const int mlane = lane & 15;
    const int quad  = lane >> 4;

    const int nCo  = C_OUT / COPB;
    const int b    = blockIdx.z / nCo;
    const int coB  = (blockIdx.z - b * nCo) * COPB + csub * 32;
    const int row0 = blockIdx.y * 16;
    const int col0 = blockIdx.x * 16;

    for (int idx = tid; idx < 18 * 18 * CH8; idx += NW * 64) {
        int pixel = idx / CH8;
        int ch    = (idx - pixel * CH8) * 8;
        int pr    = pixel / 18;
        int pc    = pixel - pr * 18;
        int gr = row0 - 1 + pr, gc = col0 - 1 + pc;
        ulonglong2 v; v.x = 0; v.y = 0;
        if ((unsigned)gr < (unsigned)H && (unsigned)gc < (unsigned)W)
            v = *(const ulonglong2*)&in[((b * H + gr) * W + gc) * C_IN + ch];
        *(ulonglong2*)&s_in[pixel * LDSTR + ch] = v;
    }
    __syncthreads();

    f32x4 acc[2][4];
    #pragma unroll
    for (int mt = 0; mt < 2; ++mt)
        #pragma unroll
        for (int t = 0; t < 4; ++t) acc[mt][t] = (f32x4)(0.f);

    #pragma unroll 1
    for (int kk = 0; kk < KSTEPS; ++kk) {
        short8 A[2][9];
        #pragma unroll
        for (int mt = 0; mt < 2; ++mt)
            #pragma unroll
            for (int tap = 0; tap < 9; ++tap)
                A[mt][tap] = *(const short8*)&wT[(tap * C_OUT + coB + mt * 16 + mlane) * C_IN
                                                 + kk * 32 + quad * 8];

        const unsigned short* sb =
            &s_in[(wv * 4 * 18 + mlane) * LDSTR + kk * 32 + quad * 8];
        #pragma unroll
        for (int t = 0; t < 4; ++t) {
            #pragma unroll
            for (int tap = 0; tap < 9; ++tap) {
                const int dy = tap / 3, dx = tap % 3;
                short8 Bf = *(const short8*)&sb[((t + dy) * 18 + dx) * LDSTR];
                acc[0][t] = __builtin_amdgcn_mfma_f32_16x16x32_bf16(A[0][tap], Bf, acc[0][t], 0, 0, 0);
                acc[1][t] = __builtin_amdgcn_mfma_f32_16x16x32_bf16(A[1][tap], Bf, acc[1][t], 0, 0, 0);
            }
        }
    }

    #pragma unroll
    for (int mt = 0; mt < 2; ++mt) {
        const int cb = coB + mt * 16 + quad * 4;
        float4 bv;
        if (bias) bv = *(const float4*)&bias[cb]; else { bv.x = bv.y = bv.z = bv.w = 0.f; }
        #pragma unroll
        for (int t = 0; t < 4; ++t) {
            const int row = row0 + wv * 4 + t, col = col0 + mlane;
            float o0 = acc[mt][t][0] + bv.x, o1 = acc[mt][t][1] + bv.y;
            float o2 = acc[mt][t][2] + bv.z, o3 = acc[mt][t][3] + bv.w;
            if (relu) {
                o0 = fmaxf(o0, 0.f); o1 = fmaxf(o1, 0.f);
                o2 = fmaxf(o2, 0.f); o3 = fmaxf(o3, 0.f);
            }
            ushort4 pk; pk.x = f2b(o0); pk.y = f2b(o1); pk.z = f2b(o2); pk.w = f2b(o3);
            *(ushort4*)&out[((b * H + row) * W + col) * C_OUT + cb] = pk;
        }
    }
}

// ---------------------------------------------------------------------------
// 3x3 conv, pad 1, stride 2, NHWC bf16. Block: 8x8 out px x (NW/4) co-blocks.
// Wave = 16 px (2 rows x 8 cols) x 32 c_out.
// ---------------------------------------------------------------------------
template <int C_IN, int C_OUT, int NW>
__global__ __launch_bounds__(NW * 64) void conv_s2_mfma(
    const unsigned short* __restrict__ in, const unsigned short* __restrict__ wT,
    const float* __restrict__ bias, unsigned short* __restrict__ out,
    int H_in, int W_in, int relu)
{
    constexpr int LDSTR  = C_IN + 8;
    constexpr int KSTEPS = C_IN / 32;
    constexpr int CH8    = C_IN / 8;
    constexpr int COPB   = 32 * (NW / 4);
    __shared__ unsigned short s_in[17 * 17 * LDSTR];

    const int tid   = threadIdx.x;
    const int wave  = tid >> 6;
    const int wv    = wave & 3;
    const int csub  = wave >> 2;
    const int lane  = tid & 63;
    const int mlane = lane & 15;
    const int quad  = lane >> 4;

    const int H_out = H_in >> 1, W_out = W_in >> 1;
    const int nCo   = C_OUT / COPB;
    const int b     = blockIdx.z / nCo;
    const int coB   = (blockIdx.z - b * nCo) * COPB + csub * 32;
    const int orow0 = blockIdx.y * 8, ocol0 = blockIdx.x * 8;
    const int irow0 = orow0 * 2 - 1,  icol0 = ocol0 * 2 - 1;

    for (int idx = tid; idx < 17 * 17 * CH8; idx += NW * 64) {
        int pixel = idx / CH8;
        int ch    = (idx - pixel * CH8) * 8;
        int pr    = pixel / 17;
        int pc    = pixel - pr * 17;
        int gr = irow0 + pr, gc = icol0 + pc;
        ulonglong2 v; v.x = 0; v.y = 0;
        if ((unsigned)gr < (unsigned)H_in && (unsigned)gc < (unsigned)W_in)
            v = *(const ulonglong2*)&in[((b * H_in + gr) * W_in + gc) * C_IN + ch];
        *(ulonglong2*)&s_in[pixel * LDSTR + ch] = v;
    }
    __syncthreads();

    f32x4 acc[2];
    acc[0] = (f32x4)(0.f); acc[1] = (f32x4)(0.f);

    const int plr = wv * 2 + (mlane >> 3);   // local out row 0..7
    const int plc = mlane & 7;               // local out col 0..7

    #pragma unroll 1
    for (int kk = 0; kk < KSTEPS; ++kk) {
        short8 A[2][9];
        #pragma unroll
        for (int mt = 0; mt < 2; ++mt)
            #pragma unroll
            for (int tap = 0; tap < 9; ++tap)
                A[mt][tap] = *(const short8*)&wT[(tap * C_OUT + coB + mt * 16 + mlane) * C_IN
                                                 + kk * 32 + quad * 8];

        const unsigned short* sb =
            &s_in[(plr * 2 * 17 + plc * 2) * LDSTR + kk * 32 + quad * 8];
        #pragma unroll
        for (int tap = 0; tap < 9; ++tap) {
            const int dy = tap / 3, dx = tap % 3;
            short8 Bf = *(const short8*)&sb[(dy * 17 + dx) * LDSTR];
            acc[0] = __builtin_amdgcn_mfma_f32_16x16x32_bf16(A[0][tap], Bf, acc[0], 0, 0, 0);
            acc[1] = __builtin_amdgcn_mfma_f32_16x16x32_bf16(A[1][tap], Bf, acc[1], 0, 0, 0);
        }
    }

    const int row = orow0 + plr, col = ocol0 + plc;
    #pragma unroll
    for (int mt = 0; mt < 2; ++mt) {
        const int cb = coB + mt * 16 + quad * 4;
        float4 bv;
        if (bias) bv = *(const float4*)&bias[cb]; else { bv.x = bv.y = bv.z = bv.w = 0.f; }
        float o0 = acc[mt][0] + bv.x, o1 = acc[mt][1] + bv.y;
        float o2 = acc[mt][2] + bv.z, o3 = acc[mt][3] + bv.w;
        if (relu) {
            o0 = fmaxf(o0, 0.f); o1 = fmaxf(o1, 0.f);
            o2 = fmaxf(o2, 0.f); o3 = fmaxf(o3, 0.f);
        }
        ushort4 pk; pk.x = f2b(o0); pk.y = f2b(o1); pk.z = f2b(o2); pk.w = f2b(o3);
        *(ushort4*)&out[((b * H_out + row) * W_out + col) * C_OUT + cb] = pk;
    }
}

// ---------------------------------------------------------------------------
// Deformable bilinear sampling, NHWC bf16, faithful-reshape offset semantics.
// Block = 1024 consecutive outputs. Offset rows (t = 2q0 .. 2q0+2*npx-1, all
// C2 channels = 4096 ushorts) staged coalesced into LDS; each thread computes
// 4 outputs (16 outstanding gathers).
// ---------------------------------------------------------------------------
__global__ __launch_bounds__(256) void deform_nhwc(
    const unsigned short* __restrict__ x, const unsigned short* __restrict__ off,
    unsigned short* __restrict__ out, int lc, int lhw, int lw)
{
    __shared__ unsigned short s_off[4096];
    const int HW = 1 << lhw, W = 1 << lw, H = HW >> lw;
    const int Cm1 = (1 << lc) - 1;
    const int lC2 = lc + 1;
    const int i0   = blockIdx.x << 10;
    const int pix0 = i0 >> lc;
    const int q0   = pix0 & (HW - 1);
    const int b    = pix0 >> lhw;
    const int ob   = b << lhw;

    const int t0base = q0 << 1;
    for (int idx = threadIdx.x; idx < 4096; idx += 256) {
        const int r = idx >> lC2;
        const int k = idx & ((1 << lC2) - 1);
        const int m = (t0base + r) & (HW - 1);
        s_off[idx] = off[((ob + m) << lC2) + k];
    }
    __syncthreads();

    float res[4];
    #pragma unroll
    for (int u = 0; u < 4; ++u) {
        const int i   = i0 + (int)threadIdx.x + (u << 8);
        const int ci  = i & Cm1;
        const int q   = (i >> lc) & (HW - 1);
        const int r   = q >> lw, c = q & (W - 1);
        const int e   = q >> (lhw - 1);          // which channel parity
        const int rl  = (q - q0) << 1;
        const float roff = b2f(s_off[(rl << lC2) + (ci << 1) + e]);
        const float coff = b2f(s_off[((rl + 1) << lC2) + (ci << 1) + e]);
        const float rr = fminf(fmaxf(roff + (float)r, 0.f), (float)(H - 1));
        const float cc = fminf(fmaxf(coff + (float)c, 0.f), (float)(W - 1));
        const float rf = floorf(rr), cf = floorf(cc);
        const int r0 = (int)rf, c0 = (int)cf;
        const int r1 = (int)ceilf(rr), c1 = (int)ceilf(cc);
        const float v_lt = b2f(x[((ob + (r0 << lw) + c0) << lc) + ci]);
        const float v_rb = b2f(x[((ob + (r1 << lw) + c1) << lc) + ci]);
        const float v_lb = b2f(x[((ob + (r0 << lw) + c1) << lc) + ci]);
        const float v_rt = b2f(x[((ob + (r1 << lw) + c0) << lc) + ci]);
        const float fr = rr - rf, fc = cc - cf;
        const float vt = v_lt + (v_rt - v_lt) * fr;
        const float vb = v_lb + (v_rb - v_lb) * fr;
        res[u] = vt + (vb - vt) * fc;
    }
    #pragma unroll
    for (int u = 0; u < 4; ++u)
        out[i0 + (int)threadIdx.x + (u << 8)] = f2b(res[u]);
}

// ---------------------------------------------------------------------------
// x: fp32 NCHW (C=32) -> bf16 NHWC via LDS transpose. Block: 32ch x 64 px.
// ---------------------------------------------------------------------------
__global__ __launch_bounds__(256) void nchw2nhwc(
    const float* __restrict__ x, unsigned short* __restrict__ out, int HW)
{
    __shared__ float s[32][65];
    const int b = blockIdx.y, p0 = blockIdx.x * 64;
    const int tid = threadIdx.x;
    #pragma unroll
    for (int k = 0; k < 8; ++k) {
        int e = tid + k * 256, ci = e >> 6, p = e & 63;
        s[ci][p] = x[(b * 32 + ci) * HW + p0 + p];
    }
    __syncthreads();
    #pragma unroll
    for (int k = 0; k < 8; ++k) {
        int e = tid + k * 256, p = e >> 5, ci = e & 31;
        out[(b * HW + p0 + p) * 32 + ci] = f2b(s[ci][p]);
    }
}

// all 7 weight transforms in one launch: fp32 OIHW -> bf16 [tap][C_out][C_in]
struct WTArgs {
    const float* src[7];
    unsigned short* dst[7];
    int co[7], ci[7], n[7];
};
__global__ __launch_bounds__(256) void wtrans_all(WTArgs a)
{
    const int i = blockIdx.x * 256 + threadIdx.x;
    #pragma unroll
    for (int s = 0; s < 7; ++s) {
        if (i < a.n[s]) {
            const int ci  = i % a.ci[s];
            const int rr  = i / a.ci[s];
            const int co  = rr % a.co[s];
            const int tap = rr / a.co[s];
            a.dst[s][i] = f2b(a.src[s][(co * a.ci[s] + ci) * 9 + tap]);
        }
    }
}

// global avg pool over 32x32, NHWC bf16 (C=32) -> fp32 (B,C)
__global__ __launch_bounds__(256) void avgpool_nhwc(
    const unsigned short* __restrict__ in, float* __restrict__ out)
{
    const int b = blockIdx.x, tid = threadIdx.x;
    const int ci = tid & 31, pg = tid >> 5;
    float s = 0.f;
    for (int k = 0; k < 128; ++k) {
        int p = pg * 128 + k;
        s += b2f(in[(b * 1024 + p) * 32 + ci]);
    }
    __shared__ float red[8][32];
    red[pg][ci] = s;
    __syncthreads();
    if (tid < 32) {
        float t = 0.f;
        #pragma unroll
        for (int j = 0; j < 8; ++j) t += red[j][tid];
        out[b * 32 + tid] = t * (1.f / 1024.f);
    }
}

__global__ __launch_bounds__(256) void sentinel(float* out, int n, float v)
{
    int i = blockIdx.x * 256 + threadIdx.x;
    if (i < n) out[i] = v;
}

extern "C" void kernel_launch(void* const* d_in, const int* in_sizes, int n_in,
                              void* d_out, int out_size, void* d_ws, size_t ws_size,
                              hipStream_t stream) {
    (void)in_sizes; (void)n_in; (void)out_size;
    const float* x   = (const float*)d_in[0];
    const float* w1  = (const float*)d_in[1];
    const float* b1  = (const float*)d_in[2];
    const float* ow1 = (const float*)d_in[3];
    const float* w2  = (const float*)d_in[4];
    const float* b2  = (const float*)d_in[5];
    const float* ow2 = (const float*)d_in[6];
    const float* w3  = (const float*)d_in[7];
    const float* b3  = (const float*)d_in[8];
    const float* ow3 = (const float*)d_in[9];
    const float* w4  = (const float*)d_in[10];
    const float* b4  = (const float*)d_in[11];
    float* out = (float*)d_out;
    unsigned short* wsu = (unsigned short*)d_ws;

    // workspace layout (ushort units)
    const size_t XB = 0;                         // 33554432
    const size_t HA = 33554432;
    const size_t OB = 67108864;
    const size_t DC = 134217728;
    const size_t WB = 167772160;
    const size_t total_us = WB + 165888;
    if (ws_size < total_us * 2) {
        sentinel<<<2, 256, 0, stream>>>(out, 512, 12345.0f);
        return;
    }
    unsigned short* xb = wsu + XB;
    unsigned short* hA = wsu + HA;
    unsigned short* oB = wsu + OB;
    unsigned short* dC = wsu + DC;
    unsigned short* wt1  = wsu + WB;
    unsigned short* owt1 = wt1 + 9216;
    unsigned short* wt2  = owt1 + 18432;
    unsigned short* owt2 = wt2 + 18432;
    unsigned short* wt3  = owt2 + 73728;
    unsigned short* owt3 = wt3 + 18432;
    unsigned short* wt4  = owt3 + 18432;

    WTArgs wa;
    wa.src[0] = w1;  wa.dst[0] = wt1;  wa.co[0] = 32;  wa.ci[0] = 32; wa.n[0] = 9216;
    wa.src[1] = ow1; wa.dst[1] = owt1; wa.co[1] = 64;  wa.ci[1] = 32; wa.n[1] = 18432;
    wa.src[2] = w2;  wa.dst[2] = wt2;  wa.co[2] = 64;  wa.ci[2] = 32; wa.n[2] = 18432;
    wa.src[3] = ow2; wa.dst[3] = owt2; wa.co[3] = 128; wa.ci[3] = 64; wa.n[3] = 73728;
    wa.src[4] = w3;  wa.dst[4] = wt3;  wa.co[4] = 32;  wa.ci[4] = 64; wa.n[4] = 18432;
    wa.src[5] = ow3; wa.dst[5] = owt3; wa.co[5] = 64;  wa.ci[5] = 32; wa.n[5] = 18432;
    wa.src[6] = w4;  wa.dst[6] = wt4;  wa.co[6] = 32;  wa.ci[6] = 32; wa.n[6] = 9216;
    wtrans_all<<<288, 256, 0, stream>>>(wa);

    nchw2nhwc<<<dim3(1024, 16), 256, 0, stream>>>(x, xb, 65536);

    // L1: conv1 (32->32, 256x256, s1, relu)
    conv_s1_mfma<32, 32, 4><<<dim3(16, 16, 16), 256, 0, stream>>>(xb, wt1, b1, hA, 256, 256, 1);
    // offconv1 (32->64): 2 co-blocks per staged tile
    conv_s1_mfma<32, 64, 8><<<dim3(16, 16, 16), 512, 0, stream>>>(hA, owt1, nullptr, oB, 256, 256, 0);
    deform_nhwc<<<32768, 256, 0, stream>>>(hA, oB, dC, 5, 16, 8);

    // L2: conv2 (32->64, s2) 256->128
    conv_s2_mfma<32, 64, 8><<<dim3(16, 16, 16), 512, 0, stream>>>(dC, wt2, b2, hA, 256, 256, 1);
    // offconv2 (64->128): 2 co-blocks per staged tile
    conv_s1_mfma<64, 128, 8><<<dim3(8, 8, 32), 512, 0, stream>>>(hA, owt2, nullptr, oB, 128, 128, 0);
    deform_nhwc<<<16384, 256, 0, stream>>>(hA, oB, dC, 6, 14, 7);

    // L3: conv3 (64->32, s2) 128->64
    conv_s2_mfma<64, 32, 4><<<dim3(8, 8, 16), 256, 0, stream>>>(dC, wt3, b3, hA, 128, 128, 1);
    // offconv3 (32->64)
    conv_s1_mfma<32, 64, 8><<<dim3(4, 4, 16), 512, 0, stream>>>(hA, owt3, nullptr, oB, 64, 64, 0);
    deform_nhwc<<<2048, 256, 0, stream>>>(hA, oB, dC, 5, 12, 6);

    // L4: conv4 (32->32, s2) 64->32
    conv_s2_mfma<32, 32, 4><<<dim3(4, 4, 16), 256, 0, stream>>>(dC, wt4, b4, hA, 64, 64, 1);
    avgpool_nhwc<<<16, 256, 0, stream>>>(hA, out);
}

// Round 4
// 679.660 us; speedup vs baseline: 5.3220x; 1.0297x over previous
//
#include <hip/hip_runtime.h>

typedef short short8 __attribute__((ext_vector_type(8)));
typedef float f32x4 __attribute__((ext_vector_type(4)));

__device__ __forceinline__ unsigned short f2b(float f) {
    unsigned u = __float_as_uint(f);
    u += 0x7fffu + ((u >> 16) & 1u);          // round-to-nearest-even
    return (unsigned short)(u >> 16);
}
__device__ __forceinline__ float b2f(unsigned short h) {
    return __uint_as_float(((unsigned)h) << 16);
}

// ---------------------------------------------------------------------------
// 3x3 conv, pad 1, stride 1, NHWC bf16, bf16 MFMA fp32 accum.
// Block: 16x16 output pixels x (NW/4) co-blocks of 32 c_out. NW waves.
// ---------------------------------------------------------------------------
template <int C_IN, int C_OUT, int NW>
__global__ __launch_bounds__(NW * 64) void conv_s1_mfma(
    const unsigned short* __restrict__ in, const unsigned short* __restrict__ wT,
    const float* __restrict__ bias, unsigned short* __restrict__ out,
    int H, int W, int relu)
{
    constexpr int LDSTR  = C_IN + 8;
    constexpr int KSTEPS = C_IN / 32;
    constexpr int CH8    = C_IN / 8;
    constexpr int COPB   = 32 * (NW / 4);
    __shared__ unsigned short s_in[18 * 18 * LDSTR];

    const int tid   = threadIdx.x;
    const int wave  = tid >> 6;
    const int wv    = wave & 3;
    const int csub  = wave >> 2;
    const int lane  = tid & 63;
    const int mlane = lane & 15;
    const int quad  = lane >> 4;

    const int nCo  = C_OUT / COPB;
    const int b    = blockIdx.z / nCo;
    const int coB  = (blockIdx.z - b * nCo) * COPB + csub * 32;
    const int row0 = blockIdx.y * 16;
    const int col0 = blockIdx.x * 16;

    for (int idx = tid; idx < 18 * 18 * CH8; idx += NW * 64) {
        int pixel = idx / CH8;
        int ch    = (idx - pixel * CH8) * 8;
        int pr    = pixel / 18;
        int pc    = pixel - pr * 18;
        int gr = row0 - 1 + pr, gc = col0 - 1 + pc;
        ulonglong2 v; v.x = 0; v.y = 0;
        if ((unsigned)gr < (unsigned)H && (unsigned)gc < (unsigned)W)
            v = *(const ulonglong2*)&in[((b * H + gr) * W + gc) * C_IN + ch];
        *(ulonglong2*)&s_in[pixel * LDSTR + ch] = v;
    }
    __syncthreads();

    f32x4 acc[2][4];
    #pragma unroll
    for (int mt = 0; mt < 2; ++mt)
        #pragma unroll
        for (int t = 0; t < 4; ++t) acc[mt][t] = (f32x4)(0.f);

    #pragma unroll 1
    for (int kk = 0; kk < KSTEPS; ++kk) {
        short8 A[2][9];
        #pragma unroll
        for (int mt = 0; mt < 2; ++mt)
            #pragma unroll
            for (int tap = 0; tap < 9; ++tap)
                A[mt][tap] = *(const short8*)&wT[(tap * C_OUT + coB + mt * 16 + mlane) * C_IN
                                                 + kk * 32 + quad * 8];

        const unsigned short* sb =
            &s_in[(wv * 4 * 18 + mlane) * LDSTR + kk * 32 + quad * 8];
        #pragma unroll
        for (int t = 0; t < 4; ++t) {
            #pragma unroll
            for (int tap = 0; tap < 9; ++tap) {
                const int dy = tap / 3, dx = tap % 3;
                short8 Bf = *(const short8*)&sb[((t + dy) * 18 + dx) * LDSTR];
                acc[0][t] = __builtin_amdgcn_mfma_f32_16x16x32_bf16(A[0][tap], Bf, acc[0][t], 0, 0, 0);
                acc[1][t] = __builtin_amdgcn_mfma_f32_16x16x32_bf16(A[1][tap], Bf, acc[1][t], 0, 0, 0);
            }
        }
    }

    #pragma unroll
    for (int mt = 0; mt < 2; ++mt) {
        const int cb = coB + mt * 16 + quad * 4;
        float4 bv;
        if (bias) bv = *(const float4*)&bias[cb]; else { bv.x = bv.y = bv.z = bv.w = 0.f; }
        #pragma unroll
        for (int t = 0; t < 4; ++t) {
            const int row = row0 + wv * 4 + t, col = col0 + mlane;
            float o0 = acc[mt][t][0] + bv.x, o1 = acc[mt][t][1] + bv.y;
            float o2 = acc[mt][t][2] + bv.z, o3 = acc[mt][t][3] + bv.w;
            if (relu) {
                o0 = fmaxf(o0, 0.f); o1 = fmaxf(o1, 0.f);
                o2 = fmaxf(o2, 0.f); o3 = fmaxf(o3, 0.f);
            }
            ushort4 pk; pk.x = f2b(o0); pk.y = f2b(o1); pk.z = f2b(o2); pk.w = f2b(o3);
            *(ushort4*)&out[((b * H + row) * W + col) * C_OUT + cb] = pk;
        }
    }
}

// ---------------------------------------------------------------------------
// 3x3 conv, pad 1, stride 2, NHWC bf16. Block: 8x8 out px x (NW/4) co-blocks.
// ---------------------------------------------------------------------------
template <int C_IN, int C_OUT, int NW>
__global__ __launch_bounds__(NW * 64) void conv_s2_mfma(
    const unsigned short* __restrict__ in, const unsigned short* __restrict__ wT,
    const float* __restrict__ bias, unsigned short* __restrict__ out,
    int H_in, int W_in, int relu)
{
    constexpr int LDSTR  = C_IN + 8;
    constexpr int KSTEPS = C_IN / 32;
    constexpr int CH8    = C_IN / 8;
    constexpr int COPB   = 32 * (NW / 4);
    __shared__ unsigned short s_in[17 * 17 * LDSTR];

    const int tid   = threadIdx.x;
    const int wave  = tid >> 6;
    const int wv    = wave & 3;
    const int csub  = wave >> 2;
    const int lane  = tid & 63;
    const int mlane = lane & 15;
    const int quad  = lane >> 4;

    const int H_out = H_in >> 1, W_out = W_in >> 1;
    const int nCo   = C_OUT / COPB;
    const int b     = blockIdx.z / nCo;
    const int coB   = (blockIdx.z - b * nCo) * COPB + csub * 32;
    const int orow0 = blockIdx.y * 8, ocol0 = blockIdx.x * 8;
    const int irow0 = orow0 * 2 - 1,  icol0 = ocol0 * 2 - 1;

    for (int idx = tid; idx < 17 * 17 * CH8; idx += NW * 64) {
        int pixel = idx / CH8;
        int ch    = (idx - pixel * CH8) * 8;
        int pr    = pixel / 17;
        int pc    = pixel - pr * 17;
        int gr = irow0 + pr, gc = icol0 + pc;
        ulonglong2 v; v.x = 0; v.y = 0;
        if ((unsigned)gr < (unsigned)H_in && (unsigned)gc < (unsigned)W_in)
            v = *(const ulonglong2*)&in[((b * H_in + gr) * W_in + gc) * C_IN + ch];
        *(ulonglong2*)&s_in[pixel * LDSTR + ch] = v;
    }
    __syncthreads();

    f32x4 acc[2];
    acc[0] = (f32x4)(0.f); acc[1] = (f32x4)(0.f);

    const int plr = wv * 2 + (mlane >> 3);
    const int plc = mlane & 7;

    #pragma unroll 1
    for (int kk = 0; kk < KSTEPS; ++kk) {
        short8 A[2][9];
        #pragma unroll
        for (int mt = 0; mt < 2; ++mt)
            #pragma unroll
            for (int tap = 0; tap < 9; ++tap)
                A[mt][tap] = *(const short8*)&wT[(tap * C_OUT + coB + mt * 16 + mlane) * C_IN
                                                 + kk * 32 + quad * 8];

        const unsigned short* sb =
            &s_in[(plr * 2 * 17 + plc * 2) * LDSTR + kk * 32 + quad * 8];
        #pragma unroll
        for (int tap = 0; tap < 9; ++tap) {
            const int dy = tap / 3, dx = tap % 3;
            short8 Bf = *(const short8*)&sb[(dy * 17 + dx) * LDSTR];
            acc[0] = __builtin_amdgcn_mfma_f32_16x16x32_bf16(A[0][tap], Bf, acc[0], 0, 0, 0);
            acc[1] = __builtin_amdgcn_mfma_f32_16x16x32_bf16(A[1][tap], Bf, acc[1], 0, 0, 0);
        }
    }

    const int row = orow0 + plr, col = ocol0 + plc;
    #pragma unroll
    for (int mt = 0; mt < 2; ++mt) {
        const int cb = coB + mt * 16 + quad * 4;
        float4 bv;
        if (bias) bv = *(const float4*)&bias[cb]; else { bv.x = bv.y = bv.z = bv.w = 0.f; }
        float o0 = acc[mt][0] + bv.x, o1 = acc[mt][1] + bv.y;
        float o2 = acc[mt][2] + bv.z, o3 = acc[mt][3] + bv.w;
        if (relu) {
            o0 = fmaxf(o0, 0.f); o1 = fmaxf(o1, 0.f);
            o2 = fmaxf(o2, 0.f); o3 = fmaxf(o3, 0.f);
        }
        ushort4 pk; pk.x = f2b(o0); pk.y = f2b(o1); pk.z = f2b(o2); pk.w = f2b(o3);
        *(ushort4*)&out[((b * H_out + row) * W_out + col) * C_OUT + cb] = pk;
    }
}

// ---------------------------------------------------------------------------
// Deformable bilinear sampling, NHWC bf16, faithful-reshape offset semantics.
// Block = 2048 consecutive outputs, 8 per thread. Offset tile (2*npx rows x
// 2C ch = 8192 ushorts = 16KB) staged with 16B vector loads. Per-thread
// invariants: ci constant (C | 256), parity e block-uniform, LDS offsets are
// compile-time immediates. ~35 VALU/output.
// ---------------------------------------------------------------------------
template <int LC>
__global__ __launch_bounds__(256) void deform_nhwc(
    const unsigned short* __restrict__ x, const unsigned short* __restrict__ off,
    unsigned short* __restrict__ out, int lhw, int lw)
{
    constexpr int C   = 1 << LC;
    constexpr int C2  = 2 << LC;
    constexpr int LC2 = LC + 1;
    constexpr int NPX = 2048 >> LC;        // pixels per block
    constexpr int ST  = 256 >> LC;         // pixel stride between u-steps
    __shared__ unsigned short s_off[8192];

    const int HW = 1 << lhw, W = 1 << lw, H = HW >> lw;
    const int tid  = threadIdx.x;
    const int i0   = blockIdx.x << 11;
    const int pix0 = i0 >> LC;
    const int q0   = pix0 & (HW - 1);
    const int b    = pix0 >> lhw;
    const int ob   = b << lhw;

    // stage offsets: rows t = 2q0 .. 2q0+2*NPX-1 (mod HW), all C2 channels
    const int t0base = q0 << 1;
    #pragma unroll
    for (int j = 0; j < 4; ++j) {
        const int flat = (tid + j * 256) * 8;            // ushort index
        const int r = flat >> LC2;
        const int k = flat & (C2 - 1);
        const int m = (t0base + r) & (HW - 1);
        *(ulonglong2*)&s_off[flat] =
            *(const ulonglong2*)&off[((ob + m) << LC2) + k];
    }
    __syncthreads();

    const int ci = (i0 + tid) & (C - 1);                  // constant over u
    const int e  = (q0 >> (lhw - 1)) & 1;                 // block-uniform parity
    const int kk = (ci << 1) + e;
    const unsigned short* so = &s_off[(((tid >> LC) << 1) << LC2) + kk];
    const unsigned short* xb2 = x + ((long)ob << LC) + ci; // uniform base + ci
    const int qt = q0 + (tid >> LC);
    const float Hm1 = (float)(H - 1), Wm1 = (float)(W - 1);
    const int dcC = C, drC = C << lw;

    float res[8];
    #pragma unroll
    for (int u = 0; u < 8; ++u) {
        const int q = qt + u * ST;
        const int r = q >> lw, c = q & (W - 1);
        // LDS reads at compile-time immediate offsets (u*1024 elems)
        const float roff = b2f(so[u * 1024]);
        const float coff = b2f(so[u * 1024 + C2]);
        const float rr = fminf(fmaxf(roff + (float)r, 0.f), Hm1);   // med3
        const float cc = fminf(fmaxf(coff + (float)c, 0.f), Wm1);
        const float rf = floorf(rr), cf = floorf(cc);
        const float fr = rr - rf,   fc = cc - cf;
        const int r0 = (int)rf, c0 = (int)cf;
        const int idx00 = ((r0 << lw) + c0) << LC;        // elems, ci in base
        const int dr = (fr > 0.f) ? drC : 0;
        const int dc = (fc > 0.f) ? dcC : 0;
        const float v00 = b2f(xb2[idx00]);
        const float v01 = b2f(xb2[idx00 + dc]);
        const float v10 = b2f(xb2[idx00 + dr]);
        const float v11 = b2f(xb2[idx00 + dr + dc]);
        const float vt = v00 + (v10 - v00) * fr;          // (r?,c0) pair
        const float vb = v01 + (v11 - v01) * fr;          // (r?,c1) pair
        res[u] = vt + (vb - vt) * fc;
    }
    #pragma unroll
    for (int u = 0; u < 8; ++u)
        out[i0 + tid + (u << 8)] = f2b(res[u]);
}

// ---------------------------------------------------------------------------
// x: fp32 NCHW (C=32) -> bf16 NHWC via LDS transpose. Block: 32ch x 64 px.
// ---------------------------------------------------------------------------
__global__ __launch_bounds__(256) void nchw2nhwc(
    const float* __restrict__ x, unsigned short* __restrict__ out, int HW)
{
    __shared__ float s[32][65];
    const int b = blockIdx.y, p0 = blockIdx.x * 64;
    const int tid = threadIdx.x;
    #pragma unroll
    for (int k = 0; k < 8; ++k) {
        int e = tid + k * 256, ci = e >> 6, p = e & 63;
        s[ci][p] = x[(b * 32 + ci) * HW + p0 + p];
    }
    __syncthreads();
    #pragma unroll
    for (int k = 0; k < 8; ++k) {
        int e = tid + k * 256, p = e >> 5, ci = e & 31;
        out[(b * HW + p0 + p) * 32 + ci] = f2b(s[ci][p]);
    }
}

// all 7 weight transforms in one launch: fp32 OIHW -> bf16 [tap][C_out][C_in]
struct WTArgs {
    const float* src[7];
    unsigned short* dst[7];
    int co[7], ci[7], n[7];
};
__global__ __launch_bounds__(256) void wtrans_all(WTArgs a)
{
    const int i = blockIdx.x * 256 + threadIdx.x;
    #pragma unroll
    for (int s = 0; s < 7; ++s) {
        if (i < a.n[s]) {
            const int ci  = i % a.ci[s];
            const int rr  = i / a.ci[s];
            const int co  = rr % a.co[s];
            const int tap = rr / a.co[s];
            a.dst[s][i] = f2b(a.src[s][(co * a.ci[s] + ci) * 9 + tap]);
        }
    }
}

// global avg pool over 32x32, NHWC bf16 (C=32) -> fp32 (B,C)
__global__ __launch_bounds__(256) void avgpool_nhwc(
    const unsigned short* __restrict__ in, float* __restrict__ out)
{
    const int b = blockIdx.x, tid = threadIdx.x;
    const int ci = tid & 31, pg = tid >> 5;
    float s = 0.f;
    for (int k = 0; k < 128; ++k) {
        int p = pg * 128 + k;
        s += b2f(in[(b * 1024 + p) * 32 + ci]);
    }
    __shared__ float red[8][32];
    red[pg][ci] = s;
    __syncthreads();
    if (tid < 32) {
        float t = 0.f;
        #pragma unroll
        for (int j = 0; j < 8; ++j) t += red[j][tid];
        out[b * 32 + tid] = t * (1.f / 1024.f);
    }
}

__global__ __launch_bounds__(256) void sentinel(float* out, int n, float v)
{
    int i = blockIdx.x * 256 + threadIdx.x;
    if (i < n) out[i] = v;
}

extern "C" void kernel_launch(void* const* d_in, const int* in_sizes, int n_in,
                              void* d_out, int out_size, void* d_ws, size_t ws_size,
                              hipStream_t stream) {
    (void)in_sizes; (void)n_in; (void)out_size;
    const float* x   = (const float*)d_in[0];
    const float* w1  = (const float*)d_in[1];
    const float* b1  = (const float*)d_in[2];
    const float* ow1 = (const float*)d_in[3];
    const float* w2  = (const float*)d_in[4];
    const float* b2  = (const float*)d_in[5];
    const float* ow2 = (const float*)d_in[6];
    const float* w3  = (const float*)d_in[7];
    const float* b3  = (const float*)d_in[8];
    const float* ow3 = (const float*)d_in[9];
    const float* w4  = (const float*)d_in[10];
    const float* b4  = (const float*)d_in[11];
    float* out = (float*)d_out;
    unsigned short* wsu = (unsigned short*)d_ws;

    const size_t XB = 0;
    const size_t HA = 33554432;
    const size_t OB = 67108864;
    const size_t DC = 134217728;
    const size_t WB = 167772160;
    const size_t total_us = WB + 165888;
    if (ws_size < total_us * 2) {
        sentinel<<<2, 256, 0, stream>>>(out, 512, 12345.0f);
        return;
    }
    unsigned short* xb = wsu + XB;
    unsigned short* hA = wsu + HA;
    unsigned short* oB = wsu + OB;
    unsigned short* dC = wsu + DC;
    unsigned short* wt1  = wsu + WB;
    unsigned short* owt1 = wt1 + 9216;
    unsigned short* wt2  = owt1 + 18432;
    unsigned short* owt2 = wt2 + 18432;
    unsigned short* wt3  = owt2 + 73728;
    unsigned short* owt3 = wt3 + 18432;
    unsigned short* wt4  = owt3 + 18432;

    WTArgs wa;
    wa.src[0] = w1;  wa.dst[0] = wt1;  wa.co[0] = 32;  wa.ci[0] = 32; wa.n[0] = 9216;
    wa.src[1] = ow1; wa.dst[1] = owt1; wa.co[1] = 64;  wa.ci[1] = 32; wa.n[1] = 18432;
    wa.src[2] = w2;  wa.dst[2] = wt2;  wa.co[2] = 64;  wa.ci[2] = 32; wa.n[2] = 18432;
    wa.src[3] = ow2; wa.dst[3] = owt2; wa.co[3] = 128; wa.ci[3] = 64; wa.n[3] = 73728;
    wa.src[4] = w3;  wa.dst[4] = wt3;  wa.co[4] = 32;  wa.ci[4] = 64; wa.n[4] = 18432;
    wa.src[5] = ow3; wa.dst[5] = owt3; wa.co[5] = 64;  wa.ci[5] = 32; wa.n[5] = 18432;
    wa.src[6] = w4;  wa.dst[6] = wt4;  wa.co[6] = 32;  wa.ci[6] = 32; wa.n[6] = 9216;
    wtrans_all<<<288, 256, 0, stream>>>(wa);

    nchw2nhwc<<<dim3(1024, 16), 256, 0, stream>>>(x, xb, 65536);

    // L1: conv1 (32->32, 256x256, s1, relu)
    conv_s1_mfma<32, 32, 4><<<dim3(16, 16, 16), 256, 0, stream>>>(xb, wt1, b1, hA, 256, 256, 1);
    // offconv1 (32->64)
    conv_s1_mfma<32, 64, 8><<<dim3(16, 16, 16), 512, 0, stream>>>(hA, owt1, nullptr, oB, 256, 256, 0);
    deform_nhwc<5><<<16384, 256, 0, stream>>>(hA, oB, dC, 16, 8);

    // L2: conv2 (32->64, s2) 256->128
    conv_s2_mfma<32, 64, 8><<<dim3(16, 16, 16), 512, 0, stream>>>(dC, wt2, b2, hA, 256, 256, 1);
    // offconv2 (64->128)
    conv_s1_mfma<64, 128, 8><<<dim3(8, 8, 32), 512, 0, stream>>>(hA, owt2, nullptr, oB, 128, 128, 0);
    deform_nhwc<6><<<8192, 256, 0, stream>>>(hA, oB, dC, 14, 7);

    // L3: conv3 (64->32, s2) 128->64
    conv_s2_mfma<64, 32, 4><<<dim3(8, 8, 16), 256, 0, stream>>>(dC, wt3, b3, hA, 128, 128, 1);
    // offconv3 (32->64)
    conv_s1_mfma<32, 64, 8><<<dim3(4, 4, 16), 512, 0, stream>>>(hA, owt3, nullptr, oB, 64, 64, 0);
    deform_nhwc<5><<<1024, 256, 0, stream>>>(hA, oB, dC, 12, 6);

    // L4: conv4 (32->32, s2) 64->32
    conv_s2_mfma<32, 32, 4><<<dim3(4, 4, 16), 256, 0, stream>>>(dC, wt4, b4, hA, 64, 64, 1);
    avgpool_nhwc<<<16, 256, 0, stream>>>(hA, out);
}